// Round 1
// baseline (26.145 us; speedup 1.0000x reference)
//
#include <hip/hip_runtime.h>
#include <hip/hip_bf16.h>

// out[b,s,d] = x[b,s,d] + pe[s,d]
// pe[s,d] = sin((s+1) * 10000^(-d/D))        if d even
//         = cos((s+1) * 10000^(-(d+1)/D))    if d odd
// Shapes fixed by the reference: B=4, S=4096, D=1024, fp32 in/out.

#define PE_S 4096
#define PE_D 1024
#define PE_B 4

__global__ __launch_bounds__(256) void pe_add_kernel(const float* __restrict__ x,
                                                     float* __restrict__ out) {
    const int idx = blockIdx.x * blockDim.x + threadIdx.x;   // over S*D/4
    const int dq = idx & (PE_D / 4 - 1);                     // which float4 along D
    const int s  = idx >> 8;                                 // D/4 = 256
    const int d0 = dq * 4;

    const float pos = (float)(s + 1);
    // inv_freq = 10000^(-exp_idx/D) = exp2(-exp_idx * log2(10000)/D)
    const float c = -13.287712379549449f / (float)PE_D;      // -log2(10000)/D

    float pe[4];
#pragma unroll
    for (int j = 0; j < 4; ++j) {
        const int d = d0 + j;
        const int exp_idx = (d & 1) ? (d + 1) : d;
        const float inv_freq = exp2f((float)exp_idx * c);
        const float angle = pos * inv_freq;
        pe[j] = (d & 1) ? __cosf(angle) : __sinf(angle);
    }

    const size_t off = (size_t)s * PE_D + d0;
    const size_t SD = (size_t)PE_S * PE_D;
#pragma unroll
    for (int b = 0; b < PE_B; ++b) {
        const float4 xv = *reinterpret_cast<const float4*>(x + b * SD + off);
        float4 ov;
        ov.x = xv.x + pe[0];
        ov.y = xv.y + pe[1];
        ov.z = xv.z + pe[2];
        ov.w = xv.w + pe[3];
        *reinterpret_cast<float4*>(out + b * SD + off) = ov;
    }
}

extern "C" void kernel_launch(void* const* d_in, const int* in_sizes, int n_in,
                              void* d_out, int out_size, void* d_ws, size_t ws_size,
                              hipStream_t stream) {
    const float* x = (const float*)d_in[0];
    float* out = (float*)d_out;

    const int threads = 256;
    const int total_quads = PE_S * (PE_D / 4);               // 1,048,576 threads
    const int blocks = total_quads / threads;                // 4096 blocks
    pe_add_kernel<<<blocks, threads, 0, stream>>>(x, out);
}

// Round 2
// 24.201 us; speedup vs baseline: 1.0803x; 1.0803x over previous
//
#include <hip/hip_runtime.h>
#include <hip/hip_bf16.h>

// out[b,s,d] = x[b,s,d] + pe[s,d]
// pe[s,d] = sin((s+1) * 10000^(-d/D))        if d even
//         = cos((s+1) * 10000^(-(d+1)/D))    if d odd
// Shapes fixed by the reference: B=4, S=4096, D=1024, fp32 in/out.
//
// Pure-stream mapping: 1 thread = 1 float4, 1 load + 1 store, sequential
// addresses across the whole tensor (matches the 6.3 TB/s copy ubench
// pattern). PE recomputed per thread: 8 transcendentals x 4M threads
// ~= 1.6 us of full-chip quarter-rate VALU — hidden under ~21 us of HBM.

#define PE_S 4096
#define PE_D 1024
#define PE_B 4

__global__ __launch_bounds__(256) void pe_add_kernel(const float* __restrict__ x,
                                                     float* __restrict__ out) {
    const int idx = blockIdx.x * blockDim.x + threadIdx.x;   // over B*S*D/4
    const int dq = idx & (PE_D / 4 - 1);                     // which float4 along D
    const int s  = (idx >> 8) & (PE_S - 1);                  // D/4 = 256 quads/row
    const int d0 = dq * 4;

    const float pos = (float)(s + 1);
    // inv_freq = 10000^(-exp_idx/D) = exp2(-exp_idx * log2(10000)/D)
    const float c = -13.287712379549449f / (float)PE_D;      // -log2(10000)/D

    float pe[4];
#pragma unroll
    for (int j = 0; j < 4; ++j) {
        const int d = d0 + j;
        const int exp_idx = (d & 1) ? (d + 1) : d;
        const float inv_freq = exp2f((float)exp_idx * c);
        const float angle = pos * inv_freq;
        pe[j] = (d & 1) ? __cosf(angle) : __sinf(angle);
    }

    const size_t off = (size_t)idx * 4;
    const float4 xv = *reinterpret_cast<const float4*>(x + off);
    float4 ov;
    ov.x = xv.x + pe[0];
    ov.y = xv.y + pe[1];
    ov.z = xv.z + pe[2];
    ov.w = xv.w + pe[3];
    *reinterpret_cast<float4*>(out + off) = ov;
}

extern "C" void kernel_launch(void* const* d_in, const int* in_sizes, int n_in,
                              void* d_out, int out_size, void* d_ws, size_t ws_size,
                              hipStream_t stream) {
    const float* x = (const float*)d_in[0];
    float* out = (float*)d_out;

    const int threads = 256;
    const int total_quads = PE_B * PE_S * (PE_D / 4);        // 4,194,304 quads
    const int blocks = total_quads / threads;                // 16384 blocks
    pe_add_kernel<<<blocks, threads, 0, stream>>>(x, out);
}